// Round 2
// baseline (50.772 us; speedup 1.0000x reference)
//
#include <hip/hip_runtime.h>
#include <hip/hip_bf16.h>

#define B_ 256
#define S_ 512
#define H_ 300
#define NL_ 7
#define NT_ 320   // block threads (5 waves); 300 active for H-dim work
#define NCHUNK_ 4
#define SPER_ (S_ / NCHUNK_)   // 128

#define NGATHER_ (B_ * NCHUNK_)          // 1024 gather blocks
#define NTILE_ 10                        // ceil(300/32)
#define NTRANS_ (2 * NTILE_ * NTILE_)    // 200 transpose blocks

// ---------------- Kernel A: gather (+compacted ids) and W1/W2 transpose ----
// blocks [0, NGATHER_): masked embedding gather partial sums.
// blocks [NGATHER_, NGATHER_+NTRANS_): 32x32 tiled transpose of W1,W2 -> ws.
__global__ __launch_bounds__(NT_) void dan_gather_t(
    const int* __restrict__ ids, const int* __restrict__ am,
    const float* __restrict__ emb,
    const float* __restrict__ W1, const float* __restrict__ W2,
    float* __restrict__ partial, float* __restrict__ WT1,
    float* __restrict__ WT2) {
  const int bid = blockIdx.x;
  const int t = threadIdx.x;

  if (bid < NGATHER_) {
    // ---- gather ----
    const int b = bid >> 2, c = bid & 3;
    __shared__ int cid[SPER_ + 8];
    __shared__ int wcnt[2];
    __shared__ int snnzp;

    int id = 0;
    if (t < SPER_) {
      int off = b * S_ + c * SPER_ + t;
      id = ids[off] * am[off];
    }
    for (int s = t; s < SPER_ + 8; s += NT_) cid[s] = 0;
    unsigned long long m = __ballot(id != 0);
    const int lane = t & 63;
    if (t < SPER_ && lane == 0) wcnt[t >> 6] = __popcll(m);
    __syncthreads();
    if (t < SPER_ && id != 0) {
      int base = (t >> 6) ? wcnt[0] : 0;
      int rank = __popcll(m & ((1ull << lane) - 1));
      cid[base + rank] = id;
    }
    if (t == 0) snnzp = (wcnt[0] + wcnt[1] + 7) & ~7;
    __syncthreads();

    if (t < H_) {
      const float* ep = emb + t;
      const int nnzp = snnzp;
      float a0 = 0.f, a1 = 0.f, a2 = 0.f, a3 = 0.f;
#pragma unroll 2
      for (int s = 0; s < nnzp; s += 8) {
        a0 += ep[(size_t)cid[s] * H_];
        a1 += ep[(size_t)cid[s + 1] * H_];
        a2 += ep[(size_t)cid[s + 2] * H_];
        a3 += ep[(size_t)cid[s + 3] * H_];
        a0 += ep[(size_t)cid[s + 4] * H_];
        a1 += ep[(size_t)cid[s + 5] * H_];
        a2 += ep[(size_t)cid[s + 6] * H_];
        a3 += ep[(size_t)cid[s + 7] * H_];
      }
      float r = (a0 + a1) + (a2 + a3) + (float)(SPER_ - nnzp) * ep[0];
      partial[bid * H_ + t] = r;
    }
  } else {
    // ---- transpose W1/W2 into ws (32x32 tiles, 320 threads as 32x10) ----
    int tid = bid - NGATHER_;
    const float* src = (tid < NTILE_ * NTILE_) ? W1 : W2;
    float* dst = (tid < NTILE_ * NTILE_) ? WT1 : WT2;
    int tile = (tid < NTILE_ * NTILE_) ? tid : tid - NTILE_ * NTILE_;
    int by = (tile / NTILE_) * 32, bx = (tile % NTILE_) * 32;
    __shared__ float stile[32][33];
    int tx = t & 31, ty = t >> 5;  // 32 x 10
    for (int r = ty; r < 32; r += 10) {
      int row = by + r, col = bx + tx;
      if (row < H_ && col < H_) stile[r][tx] = src[row * H_ + col];
    }
    __syncthreads();
    for (int r = ty; r < 32; r += 10) {
      int row = bx + r, col = by + tx;
      if (row < H_ && col < H_) dst[row * H_ + col] = stile[tx][r];
    }
  }
}

// ---------------- Kernel B: reduce partials + 3-layer MLP + logp -----------
// grid B_, block NT_. WT1/WT2 are transposed weights (coalesced reads).
__global__ __launch_bounds__(NT_) void dan_mlp(
    const float* __restrict__ partial, const int* __restrict__ drop,
    const int* __restrict__ labels,
    const float* __restrict__ WT1, const float* __restrict__ b1,
    const float* __restrict__ WT2, const float* __restrict__ b2,
    const float* __restrict__ W3, const float* __restrict__ b3,
    float* __restrict__ out, float* __restrict__ perloss) {
  const int b = blockIdx.x, t = threadIdx.x;
  __shared__ float savg[H_];
  __shared__ float sh[H_];
  __shared__ float swred[NT_ / 64];
  __shared__ float snz;
  __shared__ float slog[NL_];

  // nonzeros[b] = sum_s drop_mask[b,s]
  int nzp = 0;
  for (int s = t; s < S_; s += NT_) nzp += drop[b * S_ + s];
  for (int o = 32; o > 0; o >>= 1) nzp += __shfl_down(nzp, o, 64);
  if ((t & 63) == 0) swred[t >> 6] = (float)nzp;
  __syncthreads();
  if (t == 0) {
    float s = 0.f;
    for (int w = 0; w < NT_ / 64; ++w) s += swred[w];
    snz = s;
  }
  __syncthreads();

  if (t < H_) {
    float s = 0.f;
#pragma unroll
    for (int c = 0; c < NCHUNK_; ++c) s += partial[(b * NCHUNK_ + c) * H_ + t];
    savg[t] = s / snz;
  }
  __syncthreads();

  // h1 = relu(W1 @ avg + b1); WT1[j*H + i] = W1[i*H + j] -> coalesced over t
  if (t < H_) {
    float acc = b1[t];
    const float* w = WT1 + t;
#pragma unroll 10
    for (int j = 0; j < H_; ++j) acc = fmaf(w[(size_t)j * H_], savg[j], acc);
    sh[t] = fmaxf(acc, 0.f);
  }
  __syncthreads();

  // h2 = relu(W2 @ h1 + b2)
  if (t < H_) {
    float acc = b2[t];
    const float* w = WT2 + t;
#pragma unroll 10
    for (int j = 0; j < H_; ++j) acc = fmaf(w[(size_t)j * H_], sh[j], acc);
    savg[t] = fmaxf(acc, 0.f);
  }
  __syncthreads();

  // logits = W3 @ h2 + b3
  if (t < NL_) {
    float acc = b3[t];
    const float* w = W3 + t * H_;
    for (int j = 0; j < H_; ++j) acc = fmaf(w[j], savg[j], acc);
    slog[t] = acc;
    out[1 + b * NL_ + t] = acc;
  }
  __syncthreads();

  if (t == 0) {
    float m = slog[0];
    for (int c = 1; c < NL_; ++c) m = fmaxf(m, slog[c]);
    float se = 0.f;
    for (int c = 0; c < NL_; ++c) se += expf(slog[c] - m);
    int lab = labels[b];
    perloss[b] = slog[lab] - m - logf(se);
  }
}

// ---------------- Kernel C: deterministic loss reduction -------------------
__global__ void dan_loss(const float* __restrict__ perloss,
                         float* __restrict__ out) {
  const int t = threadIdx.x;  // 256 threads
  float v = perloss[t];
  for (int o = 32; o > 0; o >>= 1) v += __shfl_down(v, o, 64);
  __shared__ float r[4];
  if ((t & 63) == 0) r[t >> 6] = v;
  __syncthreads();
  if (t == 0) out[0] = -(r[0] + r[1] + r[2] + r[3]) * (1.0f / B_);
}

extern "C" void kernel_launch(void* const* d_in, const int* in_sizes, int n_in,
                              void* d_out, int out_size, void* d_ws,
                              size_t ws_size, hipStream_t stream) {
  const int* ids = (const int*)d_in[0];
  const int* am = (const int*)d_in[1];
  const int* labels = (const int*)d_in[2];
  const int* drop = (const int*)d_in[3];
  const float* emb = (const float*)d_in[4];
  const float* W1 = (const float*)d_in[5];
  const float* b1 = (const float*)d_in[6];
  const float* W2 = (const float*)d_in[7];
  const float* b2 = (const float*)d_in[8];
  const float* W3 = (const float*)d_in[9];
  const float* b3 = (const float*)d_in[10];
  float* out = (float*)d_out;

  float* partial = (float*)d_ws;                          // [1024][300]
  float* perloss = partial + (size_t)NGATHER_ * H_;       // [256]
  float* WT1 = perloss + B_;                              // [300][300]
  float* WT2 = WT1 + (size_t)H_ * H_;                     // [300][300]

  dan_gather_t<<<NGATHER_ + NTRANS_, NT_, 0, stream>>>(ids, am, emb, W1, W2,
                                                       partial, WT1, WT2);
  dan_mlp<<<B_, NT_, 0, stream>>>(partial, drop, labels, WT1, b1, WT2, b2, W3,
                                  b3, out, perloss);
  dan_loss<<<1, B_, 0, stream>>>(perloss, out);
}